// Round 9
// baseline (110.774 us; speedup 1.0000x reference)
//
#include <hip/hip_runtime.h>

// VQ argmin via MFMA: x [16,64,64,64] NCHW fp32, codebook [1024,64] fp32.
// dist = ||e||^2 + (-2x).e  (||x||^2 dropped).  -2x.e computed as bf16 3-way
// split GEMM (h/m/l, keep level-sum<=2 products: hh,hm,mh,hl,mm,lh) -> exact
// to ~2^-26, below fp32 rounding noise.
//
// R17: R16 (unpinned 16x16) hit 52.4us with pipes finally overlapping 1.4x,
// but 16x16's LDS floor is 30.7us/CU (each 16-row wave re-reads 12KB/phase,
// 2 MFMA/KB).  32x32x16 doubles FLOP per LDS byte (LDS floor 15.4us) and has
// a faster matrix rate (20.5us/SIMD floor).  R12-R14 failed with this shape
// because they were PINNED (setprio + asm fences around MFMA clusters, UPD
// dependent on current accs) -> serial pipes.  R17 = R13 geometry (verified
// absmax 0) x R16 protocol (verified race-free + unpinned):
//  - NO setprio, NO fences around MFMAs; only vmcnt(3)+lgkmcnt(0) before one
//    raw barrier per phase (+ a post-barrier compiler fence)
//  - ping-pong acc sets cp/cq: phase P MFMAs into one, UPD of P-1 inline-sums
//    the other (no dep on current MFMAs -> fills the MFMA issue shadow)
//  - accs seeded with ||e||^2 (C col = lane&31 = code) -> +en add gone
// 2 waves/SIMD (~200 VGPR); each SIMD's 2 waves are from DIFFERENT blocks
// (independent barrier groups -> natural anti-phase).

typedef float f4 __attribute__((ext_vector_type(4)));
typedef float f32x16 __attribute__((ext_vector_type(16)));
typedef short s8v __attribute__((ext_vector_type(8)));
typedef unsigned int u32;

#define D_DIM 64
#define HW    4096
#define ROWSB 128
#define INF_  __builtin_inff()
#define M32(a,b,c) __builtin_amdgcn_mfma_f32_32x32x16_bf16(a,b,c,0,0,0)
#define Z16 (f32x16){0.f,0.f,0.f,0.f,0.f,0.f,0.f,0.f,0.f,0.f,0.f,0.f,0.f,0.f,0.f,0.f}

__device__ __forceinline__ unsigned short bf_rne(float f) {
    u32 u = __builtin_bit_cast(u32, f);
    u32 r = u + 0x7fffu + ((u >> 16) & 1u);
    return (unsigned short)(r >> 16);
}
__device__ __forceinline__ float bf_to_f(unsigned short h) {
    u32 u = ((u32)h) << 16;
    return __builtin_bit_cast(float, u);
}
__device__ __forceinline__ void split3(float f, unsigned short& h,
                                       unsigned short& m, unsigned short& l) {
    h = bf_rne(f);
    float f1 = f - bf_to_f(h);
    m = bf_rne(f1);
    float f2 = f1 - bf_to_f(m);
    l = bf_rne(f2);
}
__device__ __forceinline__ s8v pack8(unsigned short a0, unsigned short a1,
                                     unsigned short a2, unsigned short a3,
                                     unsigned short a4, unsigned short a5,
                                     unsigned short a6, unsigned short a7) {
    uint4 u;
    u.x = a0 | ((u32)a1 << 16);
    u.y = a2 | ((u32)a3 << 16);
    u.z = a4 | ((u32)a5 << 16);
    u.w = a6 | ((u32)a7 << 16);
    return __builtin_bit_cast(s8v, u);
}

// ---- prep: split codebook into 32x32x16 B-fragment-ordered bf16 h/m/l
// chunks + enorm.  Chunk c = T*12 + s*3 + L (T = 32-code tile 0..31,
// s = kstep 0..3, L = level): 64 lanes x 16B.  lane: code = T*32 + (lane&31),
// k = s*16 + (lane>>5)*8 + j  (B[k][n]: n = lane&31, k = (lane>>5)*8 + j).
// enorm (fp32, exact) at ws + 384KB.
__global__ __launch_bounds__(64) void prep_kernel(const float* __restrict__ cb,
                                                  char* __restrict__ wsb) {
    const int blk = blockIdx.x;
    const int lane = threadIdx.x;
    if (blk < 384) {
        const int T = blk / 12;
        const int rem = blk - T * 12;
        const int s = rem / 3;
        const int L = rem - s * 3;
        const int code = T * 32 + (lane & 31);
        const int ch0 = s * 16 + (lane >> 5) * 8;
        const float* src = cb + code * 64 + ch0;
        unsigned short o[8];
#pragma unroll
        for (int j = 0; j < 8; ++j) {
            unsigned short h, m2, l;
            split3(src[j], h, m2, l);
            o[j] = (L == 0) ? h : (L == 1) ? m2 : l;
        }
        uint4 w;
        w.x = o[0] | ((u32)o[1] << 16);
        w.y = o[2] | ((u32)o[3] << 16);
        w.z = o[4] | ((u32)o[5] << 16);
        w.w = o[6] | ((u32)o[7] << 16);
        *(uint4*)(wsb + (size_t)blk * 1024 + lane * 16) = w;
    } else {
        const int k = (blk - 384) * 64 + lane;
        const f4* row = (const f4*)(cb + (size_t)k * 64);
        float sacc = 0.f;
#pragma unroll
        for (int i = 0; i < 16; ++i) {
            f4 v = row[i];
            sacc = fmaf(v.x, v.x, sacc);
            sacc = fmaf(v.y, v.y, sacc);
            sacc = fmaf(v.z, v.z, sacc);
            sacc = fmaf(v.w, v.w, sacc);
        }
        ((float*)(wsb + 384 * 1024))[k] = sacc;
    }
}

// async global->LDS, 16B per lane: LDS dest = wave-uniform base (HW adds
// lane*16); global src is per-lane (carries the lane*16 term).
__device__ __forceinline__ void gl_lds16(const char* g, char* l) {
    __builtin_amdgcn_global_load_lds(
        (const __attribute__((address_space(1))) void*)g,
        (__attribute__((address_space(3))) void*)l, 16, 0, 0);
}

// build A-frags of (-2x) for this wave's 32 rows, kstep s (k = s*16 + lh8 + j)
#define BUILD_A(s) { \
    const float* xr = (const float*)&xs4[w32 + l31][0]; \
    f4 va = *(const f4*)(xr + (s) * 16 + lh8); \
    f4 vb = *(const f4*)(xr + (s) * 16 + lh8 + 4); \
    unsigned short h0,h1,h2,h3,h4,h5,h6,h7; \
    unsigned short q0,q1,q2,q3,q4,q5,q6,q7; \
    unsigned short l0,l1,l2,l3,l4,l5,l6,l7; \
    split3(-2.f * va.x, h0, q0, l0); split3(-2.f * va.y, h1, q1, l1); \
    split3(-2.f * va.z, h2, q2, l2); split3(-2.f * va.w, h3, q3, l3); \
    split3(-2.f * vb.x, h4, q4, l4); split3(-2.f * vb.y, h5, q5, l5); \
    split3(-2.f * vb.z, h6, q6, l6); split3(-2.f * vb.w, h7, q7, l7); \
    Ah##s = pack8(h0,h1,h2,h3,h4,h5,h6,h7); \
    Am##s = pack8(q0,q1,q2,q3,q4,q5,q6,q7); \
    Al##s = pack8(l0,l1,l2,l3,l4,l5,l6,l7); \
}

// argmin update from the PREVIOUS phase's ping-pong set QS (inline sum of the
// two chains) — independent of the CURRENT phase's MFMAs.
#define U1(QS, i) { \
    float v = QS##0[i] + QS##1[i]; \
    bool pr = (v < best##i); \
    best##i = pr ? v : best##i; \
    idx##i  = pr ? kn : idx##i; \
}
#define UPDS(QS) \
    U1(QS,0)  U1(QS,1)  U1(QS,2)  U1(QS,3)  U1(QS,4)  U1(QS,5)  U1(QS,6)  U1(QS,7) \
    U1(QS,8)  U1(QS,9)  U1(QS,10) U1(QS,11) U1(QS,12) U1(QS,13) U1(QS,14) U1(QS,15)

// one phase (one 32-code tile): stage tile P+2; read 12 B-frags; 24 MFMAs in
// 2 chains into set PS; UPD previous phase from set QS; protocol waits;
// barrier; rotate.  No setprio, no fences in the body.
#define PH(PS, QS) { \
    gl_lds16(gp + stageoff,        b2 + wu); \
    gl_lds16(gp + stageoff + 1024, b2 + wu + 1024); \
    gl_lds16(gp + stageoff + 2048, b2 + wu + 2048); \
    const char* bb = b0 + lane16; \
    const float en0 = sEn[p32 + l31]; \
    _Pragma("unroll") \
    for (int _i = 0; _i < 16; ++_i) PS##0[_i] = en0; \
    PS##1 = Z16; \
    s8v B0h = *(const s8v*)(bb +     0), B0m = *(const s8v*)(bb +  1024); \
    s8v B0l = *(const s8v*)(bb +  2048); \
    s8v B1h = *(const s8v*)(bb +  3072), B1m = *(const s8v*)(bb +  4096); \
    s8v B1l = *(const s8v*)(bb +  5120); \
    PS##0 = M32(Ah0,B0h,PS##0); PS##1 = M32(Ah0,B0m,PS##1); \
    PS##0 = M32(Am0,B0h,PS##0); PS##1 = M32(Ah0,B0l,PS##1); \
    PS##0 = M32(Am0,B0m,PS##0); PS##1 = M32(Al0,B0h,PS##1); \
    PS##0 = M32(Ah1,B1h,PS##0); PS##1 = M32(Ah1,B1m,PS##1); \
    PS##0 = M32(Am1,B1h,PS##0); PS##1 = M32(Ah1,B1l,PS##1); \
    PS##0 = M32(Am1,B1m,PS##0); PS##1 = M32(Al1,B1h,PS##1); \
    s8v B2h = *(const s8v*)(bb +  6144), B2m = *(const s8v*)(bb +  7168); \
    s8v B2l = *(const s8v*)(bb +  8192); \
    s8v B3h = *(const s8v*)(bb +  9216), B3m = *(const s8v*)(bb + 10240); \
    s8v B3l = *(const s8v*)(bb + 11264); \
    PS##0 = M32(Ah2,B2h,PS##0); PS##1 = M32(Ah2,B2m,PS##1); \
    PS##0 = M32(Am2,B2h,PS##0); PS##1 = M32(Ah2,B2l,PS##1); \
    PS##0 = M32(Am2,B2m,PS##0); PS##1 = M32(Al2,B2h,PS##1); \
    PS##0 = M32(Ah3,B3h,PS##0); PS##1 = M32(Ah3,B3m,PS##1); \
    PS##0 = M32(Am3,B3h,PS##0); PS##1 = M32(Ah3,B3l,PS##1); \
    PS##0 = M32(Am3,B3m,PS##0); PS##1 = M32(Al3,B3h,PS##1); \
    { const int kn = p32 - 32 + l31; UPDS(QS) } \
    asm volatile("s_waitcnt vmcnt(3) lgkmcnt(0)" ::: "memory"); \
    __builtin_amdgcn_s_barrier(); \
    asm volatile("" ::: "memory"); \
    { char* t = b0; b0 = b1; b1 = b2; b2 = t; } \
    gp += 12288; \
    if (gp == gend) gp = wsb; \
    p32 += 32; \
}

#define BF1(i, msk) { \
    float ov = __shfl_xor(best##i, msk); \
    int   oi = __shfl_xor(idx##i,  msk); \
    bool pr = (ov < best##i) || (ov == best##i && oi < idx##i); \
    best##i = pr ? ov : best##i; \
    idx##i  = pr ? oi : idx##i; \
}
#define BFALL(msk) \
    BF1(0,msk)  BF1(1,msk)  BF1(2,msk)  BF1(3,msk) \
    BF1(4,msk)  BF1(5,msk)  BF1(6,msk)  BF1(7,msk) \
    BF1(8,msk)  BF1(9,msk)  BF1(10,msk) BF1(11,msk) \
    BF1(12,msk) BF1(13,msk) BF1(14,msk) BF1(15,msk)

__global__ __launch_bounds__(256, 2) void vq_kernel(const float* __restrict__ x,
                                                    const char* __restrict__ wsb,
                                                    int* __restrict__ out) {
    // union: xs4[128][17] f4 (34816B) lives here until A-build done, then the
    // same region becomes the 3x12288B B staging buffers.
    __shared__ __align__(16) char smem[36864];
    __shared__ float sEn[1024];
    f4 (*xs4)[17] = (f4 (*)[17])smem;
    char* const sB = smem;

    const int tid = threadIdx.x;
    const int lane = tid & 63;
    const int w = __builtin_amdgcn_readfirstlane(tid >> 6);   // wave id 0..3
    const int l31 = lane & 31;
    const int lh = lane >> 5;             // 0/1: k-half + C/D row offset
    const int lh8 = lh * 8;
    const int w32 = w * 32;
    const int wu = w * 3072;              // wave-uniform LDS stage offset
    const int lane16 = lane * 16;
    const int stageoff = wu + lane16;     // per-lane global stage offset
    const int n0 = blockIdx.x * ROWSB;
    const int b = n0 >> 12;
    const int hw0 = n0 & (HW - 1);

    // stage e-norms
    const float* enp = (const float*)(wsb + 384 * 1024);
#pragma unroll
    for (int q = 0; q < 4; ++q) sEn[q * 256 + tid] = enp[q * 256 + tid];

    // stage x tile (fp32): wave w loads channels w*16..w*16+15 of all 128 rows
    {
        const float* g = x + ((size_t)b * D_DIM + w * 16) * HW + hw0 + lane;
        float v[16], v2[16];
#pragma unroll
        for (int i = 0; i < 16; ++i) { v[i] = g[(size_t)i * HW]; v2[i] = g[(size_t)i * HW + 64]; }
#pragma unroll
        for (int j = 0; j < 4; ++j) {
            xs4[lane][w * 4 + j]      = (f4){v[4*j],  v[4*j+1],  v[4*j+2],  v[4*j+3]};
            xs4[lane + 64][w * 4 + j] = (f4){v2[4*j], v2[4*j+1], v2[4*j+2], v2[4*j+3]};
        }
    }
    __syncthreads();

    // build A frags of (-2x) for THIS wave's 32 rows: 4 ksteps x 3 levels
    s8v Ah0, Am0, Al0, Ah1, Am1, Al1, Ah2, Am2, Al2, Ah3, Am3, Al3;
    BUILD_A(0) BUILD_A(1) BUILD_A(2) BUILD_A(3)
    __syncthreads();          // all waves done with xs4 -> smem becomes sB

    // 3 rotating staging buffers (12KB = one 32-code tile), prefetch dist 2
    char* b0 = sB;                 // holds tile P   (read this phase)
    char* b1 = sB + 12288;         // holds tile P+1 (in flight / landed)
    char* b2 = sB + 24576;         // write target: tile P+2

    // prologue: issue tiles 0 and 1 (6 loads outstanding per wave)
    gl_lds16(wsb + stageoff,                b0 + wu);
    gl_lds16(wsb + stageoff + 1024,         b0 + wu + 1024);
    gl_lds16(wsb + stageoff + 2048,         b0 + wu + 2048);
    gl_lds16(wsb + 12288 + stageoff,        b1 + wu);
    gl_lds16(wsb + 12288 + stageoff + 1024, b1 + wu + 1024);
    gl_lds16(wsb + 12288 + stageoff + 2048, b1 + wu + 2048);

    float best0=INF_, best1=INF_, best2=INF_, best3=INF_;
    float best4=INF_, best5=INF_, best6=INF_, best7=INF_;
    float best8=INF_, best9=INF_, best10=INF_, best11=INF_;
    float best12=INF_, best13=INF_, best14=INF_, best15=INF_;
    int idx0=0, idx1=0, idx2=0, idx3=0, idx4=0, idx5=0, idx6=0, idx7=0;
    int idx8=0, idx9=0, idx10=0, idx11=0, idx12=0, idx13=0, idx14=0, idx15=0;

    // ping-pong accumulator sets; q starts {INF,0} so phase-(-1) UPDs no-op
    f32x16 cp0, cp1;
    f32x16 cq0, cq1 = Z16;
#pragma unroll
    for (int i = 0; i < 16; ++i) cq0[i] = INF_;

    // own tile-0 loads landed (tile-1's 3 stay in flight), THEN barrier:
    // after it, tile 0 is landed for ALL waves.
    asm volatile("s_waitcnt vmcnt(3)" ::: "memory");
    __builtin_amdgcn_s_barrier();
    asm volatile("" ::: "memory");

    const char* gp = wsb + 2 * 12288;           // global src for tile P+2
    const char* const gend = wsb + 32 * 12288;
    int p32 = 0;

#pragma unroll 1
    for (int pp = 0; pp < 16; ++pp) {
        PH(cp, cq)    // even phase: compute set p, argmin prev from set q
        PH(cq, cp)    // odd phase:  compute set q, argmin prev from set p
    }
    asm volatile("s_waitcnt vmcnt(0)" ::: "memory");   // drain before exit

    // drain the pipeline: argmin of the final phase (set q, p32 == 1024)
    { const int kn = p32 - 32 + l31; UPDS(cq) }

    // per-row argmin across the 32 cols held by this lane's 32-lane half
    BFALL(1) BFALL(2) BFALL(4) BFALL(8) BFALL(16)

    // lane l31==0 of each half holds 16 rows of this wave's 32-row stripe:
    // reg i -> row (i&3) + 8*(i>>2) + 4*lh.  4x int4 stores.
    if (l31 == 0) {
        int* op = out + n0 + w32 + lh * 4;
        int4 q0; q0.x = idx0;  q0.y = idx1;  q0.z = idx2;  q0.w = idx3;
        int4 q1; q1.x = idx4;  q1.y = idx5;  q1.z = idx6;  q1.w = idx7;
        int4 q2; q2.x = idx8;  q2.y = idx9;  q2.z = idx10; q2.w = idx11;
        int4 q3; q3.x = idx12; q3.y = idx13; q3.z = idx14; q3.w = idx15;
        *(int4*)(op)      = q0;
        *(int4*)(op + 8)  = q1;
        *(int4*)(op + 16) = q2;
        *(int4*)(op + 24) = q3;
    }
}

extern "C" void kernel_launch(void* const* d_in, const int* in_sizes, int n_in,
                              void* d_out, int out_size, void* d_ws, size_t ws_size,
                              hipStream_t stream) {
    const float* x  = (const float*)d_in[0];   // [16,64,64,64] fp32
    const float* cb = (const float*)d_in[1];   // [1024,64] fp32
    char* wsb = (char*)d_ws;                   // 384KB packed cb + 4KB enorm
    int*  out = (int*)d_out;                   // 65536 int32 indices

    prep_kernel<<<dim3(400), dim3(64), 0, stream>>>(cb, wsb);
    vq_kernel<<<dim3(65536 / ROWSB), dim3(256), 0, stream>>>(x, wsb, out);
}